// Round 1
// baseline (993.300 us; speedup 1.0000x reference)
//
#include <hip/hip_runtime.h>

#define D 64

__global__ void deg_kernel(const int* __restrict__ dst, float* __restrict__ deg, int E) {
    int i = blockIdx.x * blockDim.x + threadIdx.x;
    int stride = gridDim.x * blockDim.x;
    for (int e = i; e < E; e += stride)
        atomicAdd(&deg[dst[e]], 1.0f);
}

// One wave (64 lanes) per edge; lane d handles feature dim d.
// Coalesced 256B row gather + 64 contiguous fp32 atomics per edge.
__global__ void scatter_kernel(const float* __restrict__ feat, float* __restrict__ agg,
                               const int* __restrict__ src, const int* __restrict__ dst, int E) {
    int gw   = (blockIdx.x * blockDim.x + threadIdx.x) >> 6;
    int lane = threadIdx.x & 63;
    int nw   = (gridDim.x * blockDim.x) >> 6;
    for (int e = gw; e < E; e += nw) {
        int s = src[e];
        int t = dst[e];
        atomicAdd(&agg[t * D + lane], feat[s * D + lane]);
    }
}

// out[n,d] = (maybe relu)( (agg[n,:]/max(deg[n],1)) . Wl[d,:] + b[d] + xin[n,:] . Wr[d,:] )
// Wave per node (lane = output dim d). W matrices staged TRANSPOSED in LDS so the
// k-loop reads sW[k*64+lane]: consecutive addresses across lanes -> 2 lanes/bank (free).
// Node rows staged in LDS; sa[wid][k] is a same-address broadcast (free).
// Safe when out == xin (layer 2): each wave stages its own row before the barrier,
// computes, then overwrites it; no other block touches that row.
template<int RELU>
__global__ void combine_kernel(const float* __restrict__ xin, const float* __restrict__ agg,
                               const float* __restrict__ deg,
                               const float* __restrict__ Wl, const float* __restrict__ bias,
                               const float* __restrict__ Wr,
                               float* __restrict__ out, int n_nodes) {
    __shared__ float sWl[D * D];
    __shared__ float sWr[D * D];
    __shared__ float sb[D];
    __shared__ float srow[4][2][D];   // [wave][{agg,x}][k]

    for (int i = threadIdx.x; i < D * D; i += blockDim.x) {
        int d = i >> 6, k = i & 63;
        sWl[k * D + d] = Wl[i];   // transpose: sWl[k][d] = Wl[d][k]
        sWr[k * D + d] = Wr[i];
    }
    if (threadIdx.x < D) sb[threadIdx.x] = bias[threadIdx.x];
    __syncthreads();

    int lane = threadIdx.x & 63;
    int wid  = threadIdx.x >> 6;

    for (int base = blockIdx.x * 4; base < n_nodes; base += gridDim.x * 4) {
        int n = base + wid;
        bool valid = n < n_nodes;
        if (valid) {
            float dg = deg[n];
            dg = dg > 1.0f ? dg : 1.0f;
            srow[wid][0][lane] = agg[(size_t)n * D + lane] / dg;
            srow[wid][1][lane] = xin[(size_t)n * D + lane];
        }
        __syncthreads();
        if (valid) {
            float accL = 0.f, accR = 0.f;
            #pragma unroll
            for (int k = 0; k < D; ++k) {
                accL = fmaf(srow[wid][0][k], sWl[k * D + lane], accL);
                accR = fmaf(srow[wid][1][k], sWr[k * D + lane], accR);
            }
            float r = accL + sb[lane] + accR;
            if (RELU) r = fmaxf(r, 0.f);
            out[(size_t)n * D + lane] = r;
        }
        __syncthreads();
    }
}

extern "C" void kernel_launch(void* const* d_in, const int* in_sizes, int n_in,
                              void* d_out, int out_size, void* d_ws, size_t ws_size,
                              hipStream_t stream) {
    const float* x   = (const float*)d_in[0];
    const int*   ei  = (const int*)d_in[1];
    const float* W1l = (const float*)d_in[2];
    const float* b1  = (const float*)d_in[3];
    const float* W1r = (const float*)d_in[4];
    const float* W2l = (const float*)d_in[5];
    const float* b2  = (const float*)d_in[6];
    const float* W2r = (const float*)d_in[7];
    float* out = (float*)d_out;

    const int N = in_sizes[0] / D;     // 100000
    const int E = in_sizes[1] / 2;     // 1600000
    const int* src = ei;
    const int* dst = ei + E;

    float* deg = (float*)d_ws;
    float* agg = (float*)((char*)d_ws + (((size_t)N * 4 + 511) & ~(size_t)511));

    hipMemsetAsync(deg, 0, (size_t)N * 4, stream);
    hipMemsetAsync(agg, 0, (size_t)N * D * 4, stream);

    deg_kernel<<<2048, 256, 0, stream>>>(dst, deg, E);

    // Layer 1
    scatter_kernel<<<4096, 256, 0, stream>>>(x, agg, src, dst, E);
    combine_kernel<1><<<2048, 256, 0, stream>>>(x, agg, deg, W1l, b1, W1r, out, N);

    // Layer 2 (h lives in d_out)
    hipMemsetAsync(agg, 0, (size_t)N * D * 4, stream);
    scatter_kernel<<<4096, 256, 0, stream>>>(out, agg, src, dst, E);
    combine_kernel<0><<<2048, 256, 0, stream>>>(out, agg, deg, W2l, b2, W2r, out, N);
}

// Round 2
// 479.811 us; speedup vs baseline: 2.0702x; 2.0702x over previous
//
#include <hip/hip_runtime.h>

#define D 64

// ============================ CSR build ============================

__global__ void count_kernel(const int* __restrict__ dst, int* __restrict__ counts, int E) {
    int i = blockIdx.x * blockDim.x + threadIdx.x;
    int stride = gridDim.x * blockDim.x;
    for (int e = i; e < E; e += stride)
        atomicAdd(&counts[dst[e]], 1);
}

__global__ void scan_block_sums(const int* __restrict__ counts, int* __restrict__ partial, int N4) {
    __shared__ int sd[256];
    int idx = blockIdx.x * 256 + threadIdx.x;
    int s = 0;
    if (idx < N4) {
        int4 v = ((const int4*)counts)[idx];
        s = v.x + v.y + v.z + v.w;
    }
    sd[threadIdx.x] = s; __syncthreads();
    for (int off = 128; off > 0; off >>= 1) {
        if (threadIdx.x < off) sd[threadIdx.x] += sd[threadIdx.x + off];
        __syncthreads();
    }
    if (threadIdx.x == 0) partial[blockIdx.x] = sd[0];
}

__global__ void scan_partials(const int* __restrict__ partial, int* __restrict__ pscan,
                              int* __restrict__ rowptr, int NB, int N, int E) {
    if (threadIdx.x == 0 && blockIdx.x == 0) {
        int s = 0;
        for (int i = 0; i < NB; ++i) { pscan[i] = s; s += partial[i]; }
        rowptr[N] = E;
    }
}

// reads counts (aliased as cursor), writes rowptr[0..N) and cursor[0..N) = exclusive prefix
__global__ void scan_final(int* __restrict__ counts_cursor, const int* __restrict__ pscan,
                           int* __restrict__ rowptr, int N4) {
    __shared__ int sc[256];
    int idx = blockIdx.x * 256 + threadIdx.x;
    int4 v = make_int4(0, 0, 0, 0);
    if (idx < N4) v = ((const int4*)counts_cursor)[idx];
    int msum = v.x + v.y + v.z + v.w;
    sc[threadIdx.x] = msum; __syncthreads();
    for (int off = 1; off < 256; off <<= 1) {
        int add = (threadIdx.x >= (unsigned)off) ? sc[threadIdx.x - off] : 0;
        __syncthreads();
        sc[threadIdx.x] += add;
        __syncthreads();
    }
    int excl = sc[threadIdx.x] - msum + pscan[blockIdx.x];
    if (idx < N4) {
        int4 r;
        r.x = excl;
        r.y = excl + v.x;
        r.z = r.y + v.y;
        r.w = r.z + v.z;
        ((int4*)rowptr)[idx] = r;
        ((int4*)counts_cursor)[idx] = r;   // cursor init
    }
}

__global__ void fill_csr(const int* __restrict__ src, const int* __restrict__ dst,
                         int* __restrict__ cursor, int* __restrict__ csr, int E) {
    int i = blockIdx.x * blockDim.x + threadIdx.x;
    int stride = gridDim.x * blockDim.x;
    for (int e = i; e < E; e += stride) {
        int d = dst[e];
        int slot = atomicAdd(&cursor[d], 1);
        csr[slot] = src[e];
    }
}

// ====================== fused SAGE layer (pull) ======================
// Wave handles 8 nodes. lane = feature index. Gather-sum neighbor rows into one
// VGPR per node (lane-k layout), mean, then GEMV via v_readlane broadcast of
// agg[k]/root[k] against LDS-staged transposed W (contiguous per-lane reads,
// conflict-free). Only one __syncthreads (W staging) — waves run independently.
__device__ __forceinline__ float bcast(float v, int k) {
    return __int_as_float(__builtin_amdgcn_readlane(__float_as_int(v), k));
}

template<int RELU>
__global__ __launch_bounds__(512) void sage_fused(
        const float* __restrict__ xin, const int* __restrict__ rowptr,
        const int* __restrict__ csr,
        const float* __restrict__ Wl, const float* __restrict__ bias,
        const float* __restrict__ Wr,
        float* __restrict__ out, int n_nodes) {
    __shared__ float sWl[D * D];
    __shared__ float sWr[D * D];
    __shared__ float sb[D];
    for (int i = threadIdx.x; i < D * D; i += blockDim.x) {
        int d = i >> 6, k = i & 63;
        sWl[k * D + d] = Wl[i];   // transpose: sW[k][d]
        sWr[k * D + d] = Wr[i];
    }
    if (threadIdx.x < D) sb[threadIdx.x] = bias[threadIdx.x];
    __syncthreads();

    const int lane = threadIdx.x & 63;
    const int wid = threadIdx.x >> 6;
    const int wavesPerBlock = blockDim.x >> 6;
    const int gwave = blockIdx.x * wavesPerBlock + wid;
    const int nwaves = gridDim.x * wavesPerBlock;

    for (int base = gwave * 8; base < n_nodes; base += nwaves * 8) {
        float mean[8], root[8];
        #pragma unroll
        for (int i = 0; i < 8; ++i) {
            int n = base + i;
            float acc = 0.f;
            float inv = 0.f;
            if (n < n_nodes) {
                int r0 = rowptr[n], r1 = rowptr[n + 1];
                int j = r0;
                for (; j + 4 <= r1; j += 4) {
                    int s0 = csr[j], s1 = csr[j + 1], s2 = csr[j + 2], s3 = csr[j + 3];
                    float a0 = xin[(size_t)s0 * D + lane];
                    float a1 = xin[(size_t)s1 * D + lane];
                    float a2 = xin[(size_t)s2 * D + lane];
                    float a3 = xin[(size_t)s3 * D + lane];
                    acc += (a0 + a1) + (a2 + a3);
                }
                for (; j < r1; ++j) acc += xin[(size_t)csr[j] * D + lane];
                int deg = r1 - r0;
                inv = 1.0f / (float)(deg > 0 ? deg : 1);
                root[i] = xin[(size_t)n * D + lane];
            } else {
                root[i] = 0.f;
            }
            mean[i] = acc * inv;
        }
        float o[8];
        #pragma unroll
        for (int i = 0; i < 8; ++i) o[i] = sb[lane];
        #pragma unroll 8
        for (int k = 0; k < D; ++k) {
            float wl = sWl[k * D + lane];
            float wr = sWr[k * D + lane];
            #pragma unroll
            for (int i = 0; i < 8; ++i) {
                o[i] = fmaf(bcast(mean[i], k), wl, o[i]);
                o[i] = fmaf(bcast(root[i], k), wr, o[i]);
            }
        }
        #pragma unroll
        for (int i = 0; i < 8; ++i) {
            int n = base + i;
            if (n < n_nodes)
                out[(size_t)n * D + lane] = RELU ? fmaxf(o[i], 0.f) : o[i];
        }
    }
}

// ====================== round-1 fallback (small ws) ======================

__global__ void deg_kernel(const int* __restrict__ dst, float* __restrict__ deg, int E) {
    int i = blockIdx.x * blockDim.x + threadIdx.x;
    int stride = gridDim.x * blockDim.x;
    for (int e = i; e < E; e += stride)
        atomicAdd(&deg[dst[e]], 1.0f);
}

__global__ void scatter_kernel(const float* __restrict__ feat, float* __restrict__ agg,
                               const int* __restrict__ src, const int* __restrict__ dst, int E) {
    int gw = (blockIdx.x * blockDim.x + threadIdx.x) >> 6;
    int lane = threadIdx.x & 63;
    int nw = (gridDim.x * blockDim.x) >> 6;
    for (int e = gw; e < E; e += nw) {
        atomicAdd(&agg[(size_t)dst[e] * D + lane], feat[(size_t)src[e] * D + lane]);
    }
}

template<int RELU>
__global__ void combine_kernel(const float* __restrict__ xin, const float* __restrict__ agg,
                               const float* __restrict__ deg,
                               const float* __restrict__ Wl, const float* __restrict__ bias,
                               const float* __restrict__ Wr,
                               float* __restrict__ out, int n_nodes) {
    __shared__ float sWl[D * D];
    __shared__ float sWr[D * D];
    __shared__ float sb[D];
    __shared__ float srow[4][2][D];
    for (int i = threadIdx.x; i < D * D; i += blockDim.x) {
        int d = i >> 6, k = i & 63;
        sWl[k * D + d] = Wl[i];
        sWr[k * D + d] = Wr[i];
    }
    if (threadIdx.x < D) sb[threadIdx.x] = bias[threadIdx.x];
    __syncthreads();
    int lane = threadIdx.x & 63;
    int wid = threadIdx.x >> 6;
    for (int base = blockIdx.x * 4; base < n_nodes; base += gridDim.x * 4) {
        int n = base + wid;
        bool valid = n < n_nodes;
        if (valid) {
            float dg = deg[n];
            dg = dg > 1.0f ? dg : 1.0f;
            srow[wid][0][lane] = agg[(size_t)n * D + lane] / dg;
            srow[wid][1][lane] = xin[(size_t)n * D + lane];
        }
        __syncthreads();
        if (valid) {
            float accL = 0.f, accR = 0.f;
            #pragma unroll
            for (int k = 0; k < D; ++k) {
                accL = fmaf(srow[wid][0][k], sWl[k * D + lane], accL);
                accR = fmaf(srow[wid][1][k], sWr[k * D + lane], accR);
            }
            float r = accL + sb[lane] + accR;
            if (RELU) r = fmaxf(r, 0.f);
            out[(size_t)n * D + lane] = r;
        }
        __syncthreads();
    }
}

// ============================ launch ============================

extern "C" void kernel_launch(void* const* d_in, const int* in_sizes, int n_in,
                              void* d_out, int out_size, void* d_ws, size_t ws_size,
                              hipStream_t stream) {
    const float* x   = (const float*)d_in[0];
    const int*   ei  = (const int*)d_in[1];
    const float* W1l = (const float*)d_in[2];
    const float* b1  = (const float*)d_in[3];
    const float* W1r = (const float*)d_in[4];
    const float* W2l = (const float*)d_in[5];
    const float* b2  = (const float*)d_in[6];
    const float* W2r = (const float*)d_in[7];
    float* out = (float*)d_out;

    const int N = in_sizes[0] / D;   // 100000
    const int E = in_sizes[1] / 2;   // 1600000
    const int* src = ei;
    const int* dst = ei + E;

    const int N4 = N / 4;                 // N divisible by 4
    const int NB = (N4 + 255) / 256;      // scan blocks

    // ws layout (512B aligned)
    size_t off = 0;
    auto alloc = [&](size_t bytes) { size_t r = off; off += (bytes + 511) & ~(size_t)511; return r; };
    size_t o_cursor = alloc((size_t)N * 4);         // counts, then cursor
    size_t o_rowptr = alloc((size_t)(N + 1) * 4);
    size_t o_part   = alloc((size_t)NB * 4);
    size_t o_pscan  = alloc((size_t)NB * 4);
    size_t o_csr    = alloc((size_t)E * 4);
    size_t o_h      = alloc((size_t)N * D * 4);
    size_t need = off;

    if (ws_size >= need) {
        int* cursor  = (int*)((char*)d_ws + o_cursor);
        int* rowptr  = (int*)((char*)d_ws + o_rowptr);
        int* partial = (int*)((char*)d_ws + o_part);
        int* pscan   = (int*)((char*)d_ws + o_pscan);
        int* csr     = (int*)((char*)d_ws + o_csr);
        float* h     = (float*)((char*)d_ws + o_h);

        hipMemsetAsync(cursor, 0, (size_t)N * 4, stream);
        count_kernel<<<2048, 256, 0, stream>>>(dst, cursor, E);
        scan_block_sums<<<NB, 256, 0, stream>>>(cursor, partial, N4);
        scan_partials<<<1, 64, 0, stream>>>(partial, pscan, rowptr, NB, N, E);
        scan_final<<<NB, 256, 0, stream>>>(cursor, pscan, rowptr, N4);
        fill_csr<<<2048, 256, 0, stream>>>(src, dst, cursor, csr, E);

        int waves = (N + 7) / 8;
        int blocks = (waves + 7) / 8;    // 8 waves (512 threads) per block
        sage_fused<1><<<blocks, 512, 0, stream>>>(x, rowptr, csr, W1l, b1, W1r, h, N);
        sage_fused<0><<<blocks, 512, 0, stream>>>(h, rowptr, csr, W2l, b2, W2r, out, N);
    } else {
        // fallback: round-1 atomic scatter path (ws >= ~26MB proven)
        float* deg = (float*)d_ws;
        float* agg = (float*)((char*)d_ws + (((size_t)N * 4 + 511) & ~(size_t)511));
        hipMemsetAsync(deg, 0, (size_t)N * 4, stream);
        hipMemsetAsync(agg, 0, (size_t)N * D * 4, stream);
        deg_kernel<<<2048, 256, 0, stream>>>(dst, deg, E);
        scatter_kernel<<<4096, 256, 0, stream>>>(x, agg, src, dst, E);
        combine_kernel<1><<<2048, 256, 0, stream>>>(x, agg, deg, W1l, b1, W1r, out, N);
        hipMemsetAsync(agg, 0, (size_t)N * D * 4, stream);
        scatter_kernel<<<4096, 256, 0, stream>>>(out, agg, src, dst, E);
        combine_kernel<0><<<2048, 256, 0, stream>>>(out, agg, deg, W2l, b2, W2r, out, N);
    }
}

// Round 3
// 348.455 us; speedup vs baseline: 2.8506x; 1.3770x over previous
//
#include <hip/hip_runtime.h>

#define D 64

// ============================ CSR build ============================

// counts via atomic; rank[e] = this edge's slot within its dst row (free from atomicAdd)
__global__ void count_rank_kernel(const int* __restrict__ dst, int* __restrict__ counts,
                                  int* __restrict__ rank, int E) {
    int t = blockIdx.x * blockDim.x + threadIdx.x;
    int stride = gridDim.x * blockDim.x;
    int E4 = E >> 2;
    for (int e4 = t; e4 < E4; e4 += stride) {
        int4 d = ((const int4*)dst)[e4];
        int4 rk;
        rk.x = atomicAdd(&counts[d.x], 1);
        rk.y = atomicAdd(&counts[d.y], 1);
        rk.z = atomicAdd(&counts[d.z], 1);
        rk.w = atomicAdd(&counts[d.w], 1);
        ((int4*)rank)[e4] = rk;
    }
    for (int e = (E & ~3) + t; e < E; e += stride)
        rank[e] = atomicAdd(&counts[dst[e]], 1);
}

__global__ void scan_block_sums(const int* __restrict__ counts, int* __restrict__ partial, int N4) {
    __shared__ int sd[256];
    int idx = blockIdx.x * 256 + threadIdx.x;
    int s = 0;
    if (idx < N4) {
        int4 v = ((const int4*)counts)[idx];
        s = v.x + v.y + v.z + v.w;
    }
    sd[threadIdx.x] = s; __syncthreads();
    for (int off = 128; off > 0; off >>= 1) {
        if (threadIdx.x < off) sd[threadIdx.x] += sd[threadIdx.x + off];
        __syncthreads();
    }
    if (threadIdx.x == 0) partial[blockIdx.x] = sd[0];
}

__global__ void scan_partials(const int* __restrict__ partial, int* __restrict__ pscan,
                              int* __restrict__ rowptr, int NB, int N, int E) {
    if (threadIdx.x == 0 && blockIdx.x == 0) {
        int s = 0;
        for (int i = 0; i < NB; ++i) { pscan[i] = s; s += partial[i]; }
        rowptr[N] = E;
    }
}

__global__ void scan_final(const int* __restrict__ counts, const int* __restrict__ pscan,
                           int* __restrict__ rowptr, int N4) {
    __shared__ int sc[256];
    int idx = blockIdx.x * 256 + threadIdx.x;
    int4 v = make_int4(0, 0, 0, 0);
    if (idx < N4) v = ((const int4*)counts)[idx];
    int msum = v.x + v.y + v.z + v.w;
    sc[threadIdx.x] = msum; __syncthreads();
    for (int off = 1; off < 256; off <<= 1) {
        int add = (threadIdx.x >= (unsigned)off) ? sc[threadIdx.x - off] : 0;
        __syncthreads();
        sc[threadIdx.x] += add;
        __syncthreads();
    }
    int excl = sc[threadIdx.x] - msum + pscan[blockIdx.x];
    if (idx < N4) {
        int4 r;
        r.x = excl;
        r.y = excl + v.x;
        r.z = r.y + v.y;
        r.w = r.z + v.z;
        ((int4*)rowptr)[idx] = r;
    }
}

// atomic-free fill: slot = rowptr[dst] + rank
__global__ void fill_csr2(const int* __restrict__ src, const int* __restrict__ dst,
                          const int* __restrict__ rowptr, const int* __restrict__ rank,
                          int* __restrict__ csr, int E) {
    int t = blockIdx.x * blockDim.x + threadIdx.x;
    int stride = gridDim.x * blockDim.x;
    int E4 = E >> 2;
    for (int e4 = t; e4 < E4; e4 += stride) {
        int4 d = ((const int4*)dst)[e4];
        int4 rk = ((const int4*)rank)[e4];
        int4 s = ((const int4*)src)[e4];
        csr[rowptr[d.x] + rk.x] = s.x;
        csr[rowptr[d.y] + rk.y] = s.y;
        csr[rowptr[d.z] + rk.z] = s.z;
        csr[rowptr[d.w] + rk.w] = s.w;
    }
    for (int e = (E & ~3) + t; e < E; e += stride)
        csr[rowptr[dst[e]] + rank[e]] = src[e];
}

// ====================== fused SAGE layer (pull, float4 gather) ======================
// Wave = 64 lanes = 4 row-subgroups (r) x 16 float4-columns (f4). Per node: gather 4
// neighbor rows per iteration with global_load_dwordx4 (16B/lane), butterfly-reduce
// across subgroups, then GEMV via readlane broadcast against LDS-staged W^T (ld=65,
// conflict-free both staging-write and read).
__device__ __forceinline__ float bcast(float v, int k) {
    return __int_as_float(__builtin_amdgcn_readlane(__float_as_int(v), k));
}

template<int RELU>
__global__ __launch_bounds__(512, 4) void sage_fused2(
        const float* __restrict__ xin, const int* __restrict__ rowptr,
        const int* __restrict__ csr,
        const float* __restrict__ Wl, const float* __restrict__ bias,
        const float* __restrict__ Wr,
        float* __restrict__ out, int n_nodes) {
    __shared__ float sWl[D * 65];
    __shared__ float sWr[D * 65];
    __shared__ float sb[D];
    for (int i = threadIdx.x; i < D * D; i += blockDim.x) {
        int d = i >> 6, k = i & 63;
        sWl[k * 65 + d] = Wl[i];   // sW[k][d] = W[d][k], padded ld=65 (conflict-free write & read)
        sWr[k * 65 + d] = Wr[i];
    }
    if (threadIdx.x < D) sb[threadIdx.x] = bias[threadIdx.x];
    __syncthreads();

    const int lane = threadIdx.x & 63;
    const int r    = lane >> 4;    // neighbor-row slot 0..3
    const int f4   = lane & 15;    // float4 column
    const int wid  = threadIdx.x >> 6;
    const int wavesPerBlock = blockDim.x >> 6;
    const int gwave = blockIdx.x * wavesPerBlock + wid;
    const int nwaves = gridDim.x * wavesPerBlock;
    const float4* __restrict__ xin4 = (const float4*)xin;

    for (int base = gwave * 8; base < n_nodes; base += nwaves * 8) {
        float4 macc[8];
        float root[8];
        #pragma unroll
        for (int i = 0; i < 8; ++i) {
            int n = base + i;
            float4 acc = make_float4(0.f, 0.f, 0.f, 0.f);
            float iv = 0.f;
            if (n < n_nodes) {
                int r0 = rowptr[n], r1 = rowptr[n + 1];
                int j = r0;
                for (; j + 8 <= r1; j += 8) {          // 8 edges per iter, 2 gathers in flight
                    int s0 = csr[j + r];
                    int s1 = csr[j + 4 + r];
                    float4 a0 = xin4[(size_t)s0 * 16 + f4];
                    float4 a1 = xin4[(size_t)s1 * 16 + f4];
                    acc.x += a0.x + a1.x; acc.y += a0.y + a1.y;
                    acc.z += a0.z + a1.z; acc.w += a0.w + a1.w;
                }
                for (; j < r1; j += 4) {               // masked tail
                    int jj = j + r;
                    if (jj < r1) {
                        float4 a = xin4[(size_t)csr[jj] * 16 + f4];
                        acc.x += a.x; acc.y += a.y; acc.z += a.z; acc.w += a.w;
                    }
                }
                int deg = r1 - r0;
                iv = 1.0f / (float)(deg > 0 ? deg : 1);
                root[i] = xin[(size_t)n * D + lane];
            } else {
                root[i] = 0.f;
            }
            // butterfly across the 4 row-subgroups: every lane ends with full column sum
            acc.x += __shfl_xor(acc.x, 16, 64);
            acc.y += __shfl_xor(acc.y, 16, 64);
            acc.z += __shfl_xor(acc.z, 16, 64);
            acc.w += __shfl_xor(acc.w, 16, 64);
            acc.x += __shfl_xor(acc.x, 32, 64);
            acc.y += __shfl_xor(acc.y, 32, 64);
            acc.z += __shfl_xor(acc.z, 32, 64);
            acc.w += __shfl_xor(acc.w, 32, 64);
            macc[i].x = acc.x * iv;
            macc[i].y = acc.y * iv;
            macc[i].z = acc.z * iv;
            macc[i].w = acc.w * iv;
        }

        float o[8];
        #pragma unroll
        for (int i = 0; i < 8; ++i) o[i] = sb[lane];
        #pragma unroll 2
        for (int kb = 0; kb < D; kb += 8) {
            #pragma unroll
            for (int u = 0; u < 8; ++u) {
                int k = kb + u;
                float wl = sWl[k * 65 + lane];
                float wr = sWr[k * 65 + lane];
                int blane = (kb >> 2) + (u >> 2);      // uniform SGPR lane select
                #pragma unroll
                for (int i = 0; i < 8; ++i) {
                    float mv;
                    switch (u & 3) {                   // compile-time component
                        case 0:  mv = bcast(macc[i].x, blane); break;
                        case 1:  mv = bcast(macc[i].y, blane); break;
                        case 2:  mv = bcast(macc[i].z, blane); break;
                        default: mv = bcast(macc[i].w, blane); break;
                    }
                    o[i] = fmaf(mv, wl, o[i]);
                    o[i] = fmaf(bcast(root[i], k), wr, o[i]);
                }
            }
        }
        #pragma unroll
        for (int i = 0; i < 8; ++i) {
            int n = base + i;
            if (n < n_nodes)
                out[(size_t)n * D + lane] = RELU ? fmaxf(o[i], 0.f) : o[i];
        }
    }
}

// ====================== fallback (small ws): round-1 atomic path ======================

__global__ void deg_kernel(const int* __restrict__ dst, float* __restrict__ deg, int E) {
    int i = blockIdx.x * blockDim.x + threadIdx.x;
    int stride = gridDim.x * blockDim.x;
    for (int e = i; e < E; e += stride)
        atomicAdd(&deg[dst[e]], 1.0f);
}

__global__ void scatter_kernel(const float* __restrict__ feat, float* __restrict__ agg,
                               const int* __restrict__ src, const int* __restrict__ dst, int E) {
    int gw = (blockIdx.x * blockDim.x + threadIdx.x) >> 6;
    int lane = threadIdx.x & 63;
    int nw = (gridDim.x * blockDim.x) >> 6;
    for (int e = gw; e < E; e += nw)
        atomicAdd(&agg[(size_t)dst[e] * D + lane], feat[(size_t)src[e] * D + lane]);
}

template<int RELU>
__global__ void combine_kernel(const float* __restrict__ xin, const float* __restrict__ agg,
                               const float* __restrict__ deg,
                               const float* __restrict__ Wl, const float* __restrict__ bias,
                               const float* __restrict__ Wr,
                               float* __restrict__ out, int n_nodes) {
    __shared__ float sWl[D * 65];
    __shared__ float sWr[D * 65];
    __shared__ float sb[D];
    __shared__ float srow[4][2][D];
    for (int i = threadIdx.x; i < D * D; i += blockDim.x) {
        int d = i >> 6, k = i & 63;
        sWl[k * 65 + d] = Wl[i];
        sWr[k * 65 + d] = Wr[i];
    }
    if (threadIdx.x < D) sb[threadIdx.x] = bias[threadIdx.x];
    __syncthreads();
    int lane = threadIdx.x & 63;
    int wid = threadIdx.x >> 6;
    for (int base = blockIdx.x * 4; base < n_nodes; base += gridDim.x * 4) {
        int n = base + wid;
        bool valid = n < n_nodes;
        if (valid) {
            float dg = deg[n];
            dg = dg > 1.0f ? dg : 1.0f;
            srow[wid][0][lane] = agg[(size_t)n * D + lane] / dg;
            srow[wid][1][lane] = xin[(size_t)n * D + lane];
        }
        __syncthreads();
        if (valid) {
            float accL = 0.f, accR = 0.f;
            #pragma unroll
            for (int k = 0; k < D; ++k) {
                accL = fmaf(srow[wid][0][k], sWl[k * 65 + lane], accL);
                accR = fmaf(srow[wid][1][k], sWr[k * 65 + lane], accR);
            }
            float rr = accL + sb[lane] + accR;
            if (RELU) rr = fmaxf(rr, 0.f);
            out[(size_t)n * D + lane] = rr;
        }
        __syncthreads();
    }
}

// ============================ launch ============================

extern "C" void kernel_launch(void* const* d_in, const int* in_sizes, int n_in,
                              void* d_out, int out_size, void* d_ws, size_t ws_size,
                              hipStream_t stream) {
    const float* x   = (const float*)d_in[0];
    const int*   ei  = (const int*)d_in[1];
    const float* W1l = (const float*)d_in[2];
    const float* b1  = (const float*)d_in[3];
    const float* W1r = (const float*)d_in[4];
    const float* W2l = (const float*)d_in[5];
    const float* b2  = (const float*)d_in[6];
    const float* W2r = (const float*)d_in[7];
    float* out = (float*)d_out;

    const int N = in_sizes[0] / D;   // 100000
    const int E = in_sizes[1] / 2;   // 1600000
    const int* src = ei;
    const int* dst = ei + E;

    const int N4 = N / 4;                 // N divisible by 4
    const int NB = (N4 + 255) / 256;

    size_t off = 0;
    auto alloc = [&](size_t bytes) { size_t r = off; off += (bytes + 511) & ~(size_t)511; return r; };
    size_t o_counts = alloc((size_t)N * 4);
    size_t o_rowptr = alloc((size_t)(N + 1) * 4);
    size_t o_part   = alloc((size_t)NB * 4);
    size_t o_pscan  = alloc((size_t)NB * 4);
    size_t o_csr    = alloc((size_t)E * 4);
    size_t o_h      = alloc((size_t)N * D * 4);   // h also hosts rank (dead before h is written)
    size_t need = off;

    if (ws_size >= need && (N & 3) == 0 && E >= 4) {
        int* counts  = (int*)((char*)d_ws + o_counts);
        int* rowptr  = (int*)((char*)d_ws + o_rowptr);
        int* partial = (int*)((char*)d_ws + o_part);
        int* pscan   = (int*)((char*)d_ws + o_pscan);
        int* csr     = (int*)((char*)d_ws + o_csr);
        float* h     = (float*)((char*)d_ws + o_h);
        int* rank    = (int*)h;                    // alias: rank dead before layer-1 writes h

        hipMemsetAsync(counts, 0, (size_t)N * 4, stream);
        count_rank_kernel<<<1600, 256, 0, stream>>>(dst, counts, rank, E);
        scan_block_sums<<<NB, 256, 0, stream>>>(counts, partial, N4);
        scan_partials<<<1, 64, 0, stream>>>(partial, pscan, rowptr, NB, N, E);
        scan_final<<<NB, 256, 0, stream>>>(counts, pscan, rowptr, N4);
        fill_csr2<<<1600, 256, 0, stream>>>(src, dst, rowptr, rank, csr, E);

        sage_fused2<1><<<512, 512, 0, stream>>>(x, rowptr, csr, W1l, b1, W1r, h, N);
        sage_fused2<0><<<512, 512, 0, stream>>>(h, rowptr, csr, W2l, b2, W2r, out, N);
    } else {
        float* deg = (float*)d_ws;
        float* agg = (float*)((char*)d_ws + (((size_t)N * 4 + 511) & ~(size_t)511));
        hipMemsetAsync(deg, 0, (size_t)N * 4, stream);
        hipMemsetAsync(agg, 0, (size_t)N * D * 4, stream);
        deg_kernel<<<2048, 256, 0, stream>>>(dst, deg, E);
        scatter_kernel<<<4096, 256, 0, stream>>>(x, agg, src, dst, E);
        combine_kernel<1><<<2048, 256, 0, stream>>>(x, agg, deg, W1l, b1, W1r, out, N);
        hipMemsetAsync(agg, 0, (size_t)N * D * 4, stream);
        scatter_kernel<<<4096, 256, 0, stream>>>(out, agg, src, dst, E);
        combine_kernel<0><<<2048, 256, 0, stream>>>(out, agg, deg, W2l, b2, W2r, out, N);
    }
}

// Round 4
// 295.199 us; speedup vs baseline: 3.3648x; 1.1804x over previous
//
#include <hip/hip_runtime.h>
#include <hip/hip_fp16.h>

#define D 64

typedef _Float16 f16;
typedef _Float16 f16x8 __attribute__((ext_vector_type(8)));
typedef float f32x4 __attribute__((ext_vector_type(4)));

// ============================ fp32 -> fp16 convert ============================

__global__ void convert_f16_kernel(const float* __restrict__ in, f16* __restrict__ out, int n4) {
    int i = blockIdx.x * blockDim.x + threadIdx.x;
    int stride = gridDim.x * blockDim.x;
    for (; i < n4; i += stride) {
        float4 v = ((const float4*)in)[i];
        uint2 o;
        o.x = __builtin_bit_cast(unsigned int, __float22half2_rn(make_float2(v.x, v.y)));
        o.y = __builtin_bit_cast(unsigned int, __float22half2_rn(make_float2(v.z, v.w)));
        ((uint2*)out)[i] = o;
    }
}

// ============================ CSR build ============================

__global__ void count_rank_kernel(const int* __restrict__ dst, int* __restrict__ counts,
                                  int* __restrict__ rank, int E) {
    int t = blockIdx.x * blockDim.x + threadIdx.x;
    int stride = gridDim.x * blockDim.x;
    int E4 = E >> 2;
    for (int e4 = t; e4 < E4; e4 += stride) {
        int4 d = ((const int4*)dst)[e4];
        int4 rk;
        rk.x = atomicAdd(&counts[d.x], 1);
        rk.y = atomicAdd(&counts[d.y], 1);
        rk.z = atomicAdd(&counts[d.z], 1);
        rk.w = atomicAdd(&counts[d.w], 1);
        ((int4*)rank)[e4] = rk;
    }
    for (int e = (E & ~3) + t; e < E; e += stride)
        rank[e] = atomicAdd(&counts[dst[e]], 1);
}

__global__ void scan_block_sums(const int* __restrict__ counts, int* __restrict__ partial, int N4) {
    __shared__ int sd[256];
    int idx = blockIdx.x * 256 + threadIdx.x;
    int s = 0;
    if (idx < N4) {
        int4 v = ((const int4*)counts)[idx];
        s = v.x + v.y + v.z + v.w;
    }
    sd[threadIdx.x] = s; __syncthreads();
    for (int off = 128; off > 0; off >>= 1) {
        if (threadIdx.x < off) sd[threadIdx.x] += sd[threadIdx.x + off];
        __syncthreads();
    }
    if (threadIdx.x == 0) partial[blockIdx.x] = sd[0];
}

__global__ void scan_partials(const int* __restrict__ partial, int* __restrict__ pscan,
                              int* __restrict__ rowptr, int NB, int N, int E) {
    if (threadIdx.x == 0 && blockIdx.x == 0) {
        int s = 0;
        for (int i = 0; i < NB; ++i) { pscan[i] = s; s += partial[i]; }
        rowptr[N] = E;
    }
}

__global__ void scan_final(const int* __restrict__ counts, const int* __restrict__ pscan,
                           int* __restrict__ rowptr, int N4) {
    __shared__ int sc[256];
    int idx = blockIdx.x * 256 + threadIdx.x;
    int4 v = make_int4(0, 0, 0, 0);
    if (idx < N4) v = ((const int4*)counts)[idx];
    int msum = v.x + v.y + v.z + v.w;
    sc[threadIdx.x] = msum; __syncthreads();
    for (int off = 1; off < 256; off <<= 1) {
        int add = (threadIdx.x >= (unsigned)off) ? sc[threadIdx.x - off] : 0;
        __syncthreads();
        sc[threadIdx.x] += add;
        __syncthreads();
    }
    int excl = sc[threadIdx.x] - msum + pscan[blockIdx.x];
    if (idx < N4) {
        int4 r;
        r.x = excl;
        r.y = excl + v.x;
        r.z = r.y + v.y;
        r.w = r.z + v.z;
        ((int4*)rowptr)[idx] = r;
    }
}

__global__ void fill_csr2(const int* __restrict__ src, const int* __restrict__ dst,
                          const int* __restrict__ rowptr, const int* __restrict__ rank,
                          int* __restrict__ csr, int E) {
    int t = blockIdx.x * blockDim.x + threadIdx.x;
    int stride = gridDim.x * blockDim.x;
    int E4 = E >> 2;
    for (int e4 = t; e4 < E4; e4 += stride) {
        int4 d = ((const int4*)dst)[e4];
        int4 rk = ((const int4*)rank)[e4];
        int4 s = ((const int4*)src)[e4];
        csr[rowptr[d.x] + rk.x] = s.x;
        csr[rowptr[d.y] + rk.y] = s.y;
        csr[rowptr[d.z] + rk.z] = s.z;
        csr[rowptr[d.w] + rk.w] = s.w;
    }
    for (int e = (E & ~3) + t; e < E; e += stride)
        csr[rowptr[dst[e]] + rank[e]] = src[e];
}

// ====================== fused SAGE layer: fp16 gather + MFMA MLP ======================
// Wave = 16 nodes. Gather (fp16 rows, fp32 acc): lane = (r4 = edge slot 0..3, f8 = 8B col),
// 4 edges in flight, butterfly-reduce across r4. Mean rows -> per-wave LDS (pitch 72 f16,
// conflict-free). MLP: out[16][64] = A[16][128] x B[128][64] via 16x mfma_f32_16x16x32_f16,
// A = [mean | root], root frags read directly from fp16 feature table (coalesced, no gather).
// B = [Wl^T ; Wr^T] fp16 fragments staged once per block in LDS.
// Frag geometry: A/B lane l holds 8 consecutive k at row/col (l&15), k0 = (l>>4)*8;
// D: col = l&15, row = (l>>4)*4 + reg (m89-verified, dtype-independent).

__device__ __forceinline__ float4 h4_to_f4(uint2 u) {
    float2 fa = __half22float2(__builtin_bit_cast(__half2, u.x));
    float2 fb = __half22float2(__builtin_bit_cast(__half2, u.y));
    return make_float4(fa.x, fa.y, fb.x, fb.y);
}

template<int RELU, int OUT16>
__global__ __launch_bounds__(512) void sage_mfma(
        const f16* __restrict__ xh, const int* __restrict__ rowptr,
        const int* __restrict__ csr,
        const float* __restrict__ Wl, const float* __restrict__ bias,
        const float* __restrict__ Wr,
        f16* __restrict__ out16, float* __restrict__ out32, int n_nodes) {
    __shared__ __align__(16) f16 sB[16 * 512];    // 16 frags x 64 lanes x 8 f16 = 16 KB
    __shared__ __align__(16) f16 sA[8][16 * 72];  // per-wave 16 rows, pitch 72 f16 (conflict-free)

    // ---- stage B fragments: frag f = t*4+q ; q 0,1 -> Wl, q 2,3 -> Wr ----
    for (int u = threadIdx.x; u < 16 * 64; u += blockDim.x) {
        int f = u >> 6;
        int l = u & 63;
        int t = f >> 2, q = f & 3;
        const float* Wsel = (q < 2) ? Wl : Wr;
        int d  = t * 16 + (l & 15);
        int k0 = (q & 1) * 32 + (l >> 4) * 8;
        const float4* wp = (const float4*)(Wsel + d * 64 + k0);
        float4 w0 = wp[0], w1 = wp[1];
        uint4 pk;
        pk.x = __builtin_bit_cast(unsigned int, __float22half2_rn(make_float2(w0.x, w0.y)));
        pk.y = __builtin_bit_cast(unsigned int, __float22half2_rn(make_float2(w0.z, w0.w)));
        pk.z = __builtin_bit_cast(unsigned int, __float22half2_rn(make_float2(w1.x, w1.y)));
        pk.w = __builtin_bit_cast(unsigned int, __float22half2_rn(make_float2(w1.z, w1.w)));
        *(uint4*)&sB[f * 512 + l * 8] = pk;
    }
    __syncthreads();

    const int lane = threadIdx.x & 63;
    const int wid  = threadIdx.x >> 6;
    const int r4   = lane >> 4;     // edge slot / k-quarter
    const int f8   = lane & 15;     // 8-byte column within a 128B fp16 row / MFMA row-col
    f16* myA = &sA[wid][0];

    float bias_t[4];
    #pragma unroll
    for (int t = 0; t < 4; ++t) bias_t[t] = bias[t * 16 + f8];

    const int wavesPerBlock = blockDim.x >> 6;
    const int gwave = blockIdx.x * wavesPerBlock + wid;
    const int nwaves = gridDim.x * wavesPerBlock;
    const uint2* __restrict__ xh2 = (const uint2*)xh;

    for (int nb = gwave * 16; nb < n_nodes; nb += nwaves * 16) {
        // ---- gather + transpose 16 nodes (whole wave per node: zero divergence) ----
        #pragma unroll 1
        for (int i = 0; i < 16; ++i) {
            int n = nb + i;
            float4 acc = make_float4(0.f, 0.f, 0.f, 0.f);
            float iv = 0.f;
            if (n < n_nodes) {
                int rp0 = rowptr[n], rp1 = rowptr[n + 1];
                int j = rp0;
                for (; j + 8 <= rp1; j += 8) {      // 8 edges per iter, 2 loads in flight
                    int s0 = csr[j + r4];
                    int s1 = csr[j + 4 + r4];
                    uint2 u0 = xh2[(size_t)s0 * 16 + f8];
                    uint2 u1 = xh2[(size_t)s1 * 16 + f8];
                    float4 a0 = h4_to_f4(u0);
                    float4 a1 = h4_to_f4(u1);
                    acc.x += a0.x + a1.x; acc.y += a0.y + a1.y;
                    acc.z += a0.z + a1.z; acc.w += a0.w + a1.w;
                }
                for (; j < rp1; j += 4) {           // masked tail
                    int jj = j + r4;
                    if (jj < rp1) {
                        float4 a = h4_to_f4(xh2[(size_t)csr[jj] * 16 + f8]);
                        acc.x += a.x; acc.y += a.y; acc.z += a.z; acc.w += a.w;
                    }
                }
                int deg = rp1 - rp0;
                iv = 1.0f / (float)(deg > 0 ? deg : 1);
            }
            // butterfly across the 4 edge-slot subgroups
            acc.x += __shfl_xor(acc.x, 16, 64);
            acc.y += __shfl_xor(acc.y, 16, 64);
            acc.z += __shfl_xor(acc.z, 16, 64);
            acc.w += __shfl_xor(acc.w, 16, 64);
            acc.x += __shfl_xor(acc.x, 32, 64);
            acc.y += __shfl_xor(acc.y, 32, 64);
            acc.z += __shfl_xor(acc.z, 32, 64);
            acc.w += __shfl_xor(acc.w, 32, 64);
            // one subgroup writes the fp16 mean row (128B, contiguous, conflict-free)
            if (r4 == (i & 3)) {
                uint2 w;
                w.x = __builtin_bit_cast(unsigned int,
                        __float22half2_rn(make_float2(acc.x * iv, acc.y * iv)));
                w.y = __builtin_bit_cast(unsigned int,
                        __float22half2_rn(make_float2(acc.z * iv, acc.w * iv)));
                *(uint2*)&myA[i * 72 + f8 * 4] = w;
            }
        }

        // ---- A fragments: mean from LDS, root direct from global fp16 table ----
        f16x8 a0 = *(const f16x8*)&myA[f8 * 72 + r4 * 8];          // k 0..31
        f16x8 a1 = *(const f16x8*)&myA[f8 * 72 + 32 + r4 * 8];     // k 32..63
        int rn = nb + f8; if (rn >= n_nodes) rn = n_nodes - 1;
        const f16x8* rrow = (const f16x8*)(xh + (size_t)rn * 64);
        f16x8 a2 = rrow[r4];                                       // root k 0..31
        f16x8 a3 = rrow[4 + r4];                                   // root k 32..63

        // ---- MFMA (4 N-tiles x 4 K-chunks) + epilogue ----
        #pragma unroll
        for (int t = 0; t < 4; ++t) {
            f32x4 c = {0.f, 0.f, 0.f, 0.f};
            c = __builtin_amdgcn_mfma_f32_16x16x32_f16(a0, *(const f16x8*)&sB[(t*4+0)*512 + lane*8], c, 0, 0, 0);
            c = __builtin_amdgcn_mfma_f32_16x16x32_f16(a1, *(const f16x8*)&sB[(t*4+1)*512 + lane*8], c, 0, 0, 0);
            c = __builtin_amdgcn_mfma_f32_16x16x32_f16(a2, *(const f16x8*)&sB[(t*4+2)*512 + lane*8], c, 0, 0, 0);
            c = __builtin_amdgcn_mfma_f32_16x16x32_f16(a3, *(const f16x8*)&sB[(t*4+3)*512 + lane*8], c, 0, 0, 0);
            #pragma unroll
            for (int rr = 0; rr < 4; ++rr) {
                int n = nb + r4 * 4 + rr;           // D row = (lane>>4)*4 + reg
                if (n < n_nodes) {
                    float v = c[rr] + bias_t[t];
                    if (RELU) v = fmaxf(v, 0.f);
                    if (OUT16) out16[(size_t)n * 64 + t * 16 + f8] = (f16)v;
                    else       out32[(size_t)n * 64 + t * 16 + f8] = v;
                }
            }
        }
    }
}

// ====================== fallback (small ws): atomic scatter path ======================

__global__ void deg_kernel(const int* __restrict__ dst, float* __restrict__ deg, int E) {
    int i = blockIdx.x * blockDim.x + threadIdx.x;
    int stride = gridDim.x * blockDim.x;
    for (int e = i; e < E; e += stride)
        atomicAdd(&deg[dst[e]], 1.0f);
}

__global__ void scatter_kernel(const float* __restrict__ feat, float* __restrict__ agg,
                               const int* __restrict__ src, const int* __restrict__ dst, int E) {
    int gw = (blockIdx.x * blockDim.x + threadIdx.x) >> 6;
    int lane = threadIdx.x & 63;
    int nw = (gridDim.x * blockDim.x) >> 6;
    for (int e = gw; e < E; e += nw)
        atomicAdd(&agg[(size_t)dst[e] * D + lane], feat[(size_t)src[e] * D + lane]);
}

template<int RELU>
__global__ void combine_kernel(const float* __restrict__ xin, const float* __restrict__ agg,
                               const float* __restrict__ deg,
                               const float* __restrict__ Wl, const float* __restrict__ bias,
                               const float* __restrict__ Wr,
                               float* __restrict__ out, int n_nodes) {
    __shared__ float sWl[D * 65];
    __shared__ float sWr[D * 65];
    __shared__ float sb[D];
    __shared__ float srow[4][2][D];
    for (int i = threadIdx.x; i < D * D; i += blockDim.x) {
        int d = i >> 6, k = i & 63;
        sWl[k * 65 + d] = Wl[i];
        sWr[k * 65 + d] = Wr[i];
    }
    if (threadIdx.x < D) sb[threadIdx.x] = bias[threadIdx.x];
    __syncthreads();
    int lane = threadIdx.x & 63;
    int wid = threadIdx.x >> 6;
    for (int base = blockIdx.x * 4; base < n_nodes; base += gridDim.x * 4) {
        int n = base + wid;
        bool valid = n < n_nodes;
        if (valid) {
            float dg = deg[n];
            dg = dg > 1.0f ? dg : 1.0f;
            srow[wid][0][lane] = agg[(size_t)n * D + lane] / dg;
            srow[wid][1][lane] = xin[(size_t)n * D + lane];
        }
        __syncthreads();
        if (valid) {
            float accL = 0.f, accR = 0.f;
            #pragma unroll
            for (int k = 0; k < D; ++k) {
                accL = fmaf(srow[wid][0][k], sWl[k * 65 + lane], accL);
                accR = fmaf(srow[wid][1][k], sWr[k * 65 + lane], accR);
            }
            float rr = accL + sb[lane] + accR;
            if (RELU) rr = fmaxf(rr, 0.f);
            out[(size_t)n * D + lane] = rr;
        }
        __syncthreads();
    }
}

// ============================ launch ============================

extern "C" void kernel_launch(void* const* d_in, const int* in_sizes, int n_in,
                              void* d_out, int out_size, void* d_ws, size_t ws_size,
                              hipStream_t stream) {
    const float* x   = (const float*)d_in[0];
    const int*   ei  = (const int*)d_in[1];
    const float* W1l = (const float*)d_in[2];
    const float* b1  = (const float*)d_in[3];
    const float* W1r = (const float*)d_in[4];
    const float* W2l = (const float*)d_in[5];
    const float* b2  = (const float*)d_in[6];
    const float* W2r = (const float*)d_in[7];
    float* out = (float*)d_out;

    const int N = in_sizes[0] / D;   // 100000
    const int E = in_sizes[1] / 2;   // 1600000
    const int* src = ei;
    const int* dst = ei + E;

    const int N4 = N / 4;
    const int NB = (N4 + 255) / 256;

    size_t off = 0;
    auto alloc = [&](size_t bytes) { size_t r = off; off += (bytes + 511) & ~(size_t)511; return r; };
    size_t o_counts = alloc((size_t)N * 4);
    size_t o_rowptr = alloc((size_t)(N + 1) * 4);
    size_t o_part   = alloc((size_t)NB * 4);
    size_t o_pscan  = alloc((size_t)NB * 4);
    size_t o_csr    = alloc((size_t)E * 4);
    size_t o_xh     = alloc((size_t)N * D * 2);   // fp16 x
    size_t o_hh     = alloc((size_t)N * D * 2);   // fp16 h; also hosts rank (dead before h written)
    size_t need = off;

    bool rank_fits = (size_t)E * 4 <= (size_t)N * D * 2;

    if (ws_size >= need && (N & 3) == 0 && E >= 4 && rank_fits) {
        int* counts  = (int*)((char*)d_ws + o_counts);
        int* rowptr  = (int*)((char*)d_ws + o_rowptr);
        int* partial = (int*)((char*)d_ws + o_part);
        int* pscan   = (int*)((char*)d_ws + o_pscan);
        int* csr     = (int*)((char*)d_ws + o_csr);
        f16* xh      = (f16*)((char*)d_ws + o_xh);
        f16* hh      = (f16*)((char*)d_ws + o_hh);
        int* rank    = (int*)hh;                  // alias: rank dead before layer-1 writes hh

        convert_f16_kernel<<<1024, 256, 0, stream>>>(x, xh, N * D / 4);

        hipMemsetAsync(counts, 0, (size_t)N * 4, stream);
        count_rank_kernel<<<1600, 256, 0, stream>>>(dst, counts, rank, E);
        scan_block_sums<<<NB, 256, 0, stream>>>(counts, partial, N4);
        scan_partials<<<1, 64, 0, stream>>>(partial, pscan, rowptr, NB, N, E);
        scan_final<<<NB, 256, 0, stream>>>(counts, pscan, rowptr, N4);
        fill_csr2<<<1600, 256, 0, stream>>>(src, dst, rowptr, rank, csr, E);

        int wavesNeeded = (N + 15) / 16;          // 6250
        int blocks = (wavesNeeded + 7) / 8;       // 782 (8 waves/block)
        sage_mfma<1, 1><<<blocks, 512, 0, stream>>>(xh, rowptr, csr, W1l, b1, W1r, hh, nullptr, N);
        sage_mfma<0, 0><<<blocks, 512, 0, stream>>>(hh, rowptr, csr, W2l, b2, W2r, nullptr, out, N);
    } else {
        float* deg = (float*)d_ws;
        float* agg = (float*)((char*)d_ws + (((size_t)N * 4 + 511) & ~(size_t)511));
        hipMemsetAsync(deg, 0, (size_t)N * 4, stream);
        hipMemsetAsync(agg, 0, (size_t)N * D * 4, stream);
        deg_kernel<<<2048, 256, 0, stream>>>(dst, deg, E);
        scatter_kernel<<<4096, 256, 0, stream>>>(x, agg, src, dst, E);
        combine_kernel<1><<<2048, 256, 0, stream>>>(x, agg, deg, W1l, b1, W1r, out, N);
        hipMemsetAsync(agg, 0, (size_t)N * D * 4, stream);
        scatter_kernel<<<4096, 256, 0, stream>>>(out, agg, src, dst, E);
        combine_kernel<0><<<2048, 256, 0, stream>>>(out, agg, deg, W2l, b2, W2r, out, N);
    }
}

// Round 5
// 224.454 us; speedup vs baseline: 4.4254x; 1.3152x over previous
//
#include <hip/hip_runtime.h>
#include <hip/hip_fp16.h>

#define D 64
#define IDXCAP 384   // per-wave LDS edge-index capacity (avg batch = 256, +8 sigma)

typedef _Float16 f16;
typedef _Float16 f16x8 __attribute__((ext_vector_type(8)));
typedef float f32x4 __attribute__((ext_vector_type(4)));

// ============================ CSR build (+ fp16 convert folded in) ============================

__global__ void count_rank_convert_kernel(const int* __restrict__ dst, int* __restrict__ counts,
                                          int* __restrict__ rank, int E,
                                          const float* __restrict__ x, f16* __restrict__ xh, int n4) {
    int t = blockIdx.x * blockDim.x + threadIdx.x;
    int stride = gridDim.x * blockDim.x;
    int E4 = E >> 2;
    for (int e4 = t; e4 < E4; e4 += stride) {
        int4 d = ((const int4*)dst)[e4];
        int4 rk;
        rk.x = atomicAdd(&counts[d.x], 1);
        rk.y = atomicAdd(&counts[d.y], 1);
        rk.z = atomicAdd(&counts[d.z], 1);
        rk.w = atomicAdd(&counts[d.w], 1);
        ((int4*)rank)[e4] = rk;
    }
    for (int e = (E & ~3) + t; e < E; e += stride)
        rank[e] = atomicAdd(&counts[dst[e]], 1);
    // fp32 -> fp16 feature convert (independent work, same launch)
    for (int i = t; i < n4; i += stride) {
        float4 v = ((const float4*)x)[i];
        uint2 o;
        o.x = __builtin_bit_cast(unsigned int, __float22half2_rn(make_float2(v.x, v.y)));
        o.y = __builtin_bit_cast(unsigned int, __float22half2_rn(make_float2(v.z, v.w)));
        ((uint2*)xh)[i] = o;
    }
}

__global__ void scan_block_sums(const int* __restrict__ counts, int* __restrict__ partial, int N4) {
    __shared__ int sd[256];
    int idx = blockIdx.x * 256 + threadIdx.x;
    int s = 0;
    if (idx < N4) {
        int4 v = ((const int4*)counts)[idx];
        s = v.x + v.y + v.z + v.w;
    }
    sd[threadIdx.x] = s; __syncthreads();
    for (int off = 128; off > 0; off >>= 1) {
        if (threadIdx.x < off) sd[threadIdx.x] += sd[threadIdx.x + off];
        __syncthreads();
    }
    if (threadIdx.x == 0) partial[blockIdx.x] = sd[0];
}

__global__ void scan_partials(const int* __restrict__ partial, int* __restrict__ pscan,
                              int* __restrict__ rowptr, int NB, int N, int E) {
    if (threadIdx.x == 0 && blockIdx.x == 0) {
        int s = 0;
        for (int i = 0; i < NB; ++i) { pscan[i] = s; s += partial[i]; }
        rowptr[N] = E;
    }
}

__global__ void scan_final(const int* __restrict__ counts, const int* __restrict__ pscan,
                           int* __restrict__ rowptr, int N4) {
    __shared__ int sc[256];
    int idx = blockIdx.x * 256 + threadIdx.x;
    int4 v = make_int4(0, 0, 0, 0);
    if (idx < N4) v = ((const int4*)counts)[idx];
    int msum = v.x + v.y + v.z + v.w;
    sc[threadIdx.x] = msum; __syncthreads();
    for (int off = 1; off < 256; off <<= 1) {
        int add = (threadIdx.x >= (unsigned)off) ? sc[threadIdx.x - off] : 0;
        __syncthreads();
        sc[threadIdx.x] += add;
        __syncthreads();
    }
    int excl = sc[threadIdx.x] - msum + pscan[blockIdx.x];
    if (idx < N4) {
        int4 r;
        r.x = excl;
        r.y = excl + v.x;
        r.z = r.y + v.y;
        r.w = r.z + v.z;
        ((int4*)rowptr)[idx] = r;
    }
}

__global__ void fill_csr2(const int* __restrict__ src, const int* __restrict__ dst,
                          const int* __restrict__ rowptr, const int* __restrict__ rank,
                          int* __restrict__ csr, int E) {
    int t = blockIdx.x * blockDim.x + threadIdx.x;
    int stride = gridDim.x * blockDim.x;
    int E4 = E >> 2;
    for (int e4 = t; e4 < E4; e4 += stride) {
        int4 d = ((const int4*)dst)[e4];
        int4 rk = ((const int4*)rank)[e4];
        int4 s = ((const int4*)src)[e4];
        csr[rowptr[d.x] + rk.x] = s.x;
        csr[rowptr[d.y] + rk.y] = s.y;
        csr[rowptr[d.z] + rk.z] = s.z;
        csr[rowptr[d.w] + rk.w] = s.w;
    }
    for (int e = (E & ~3) + t; e < E; e += stride)
        csr[rowptr[dst[e]] + rank[e]] = src[e];
}

// ====================== fused SAGE layer: fp16 gather + MFMA MLP ======================
// Wave = 16 nodes. Batch edge indices staged to LDS via coalesced loads (batch edges are
// contiguous in CSR); gather uses 4 feature loads in flight (16 edges/iter), indices via
// LDS broadcast. Butterfly-reduce across the 4 edge-slot subgroups; mean rows -> per-wave
// LDS (pitch 72 f16, conflict-free). MLP: out[16][64] = [mean|root][16][128] x B[128][64]
// via 16x mfma_f32_16x16x32_f16; B fp16 fragments staged once per block.
// Frag geometry: A/B lane l holds 8 consecutive k at row/col (l&15), k0=(l>>4)*8;
// D: col=l&15, row=(l>>4)*4+reg (m89-verified).

__device__ __forceinline__ float4 h4_to_f4(uint2 u) {
    float2 fa = __half22float2(__builtin_bit_cast(__half2, u.x));
    float2 fb = __half22float2(__builtin_bit_cast(__half2, u.y));
    return make_float4(fa.x, fa.y, fb.x, fb.y);
}

#define GATHER_BODY(IP)                                                          \
    for (; j + 16 <= deg; j += 16) {                                             \
        int s0 = (IP)[j + r4];                                                   \
        int s1 = (IP)[j + 4 + r4];                                               \
        int s2 = (IP)[j + 8 + r4];                                               \
        int s3 = (IP)[j + 12 + r4];                                              \
        float4 g0 = h4_to_f4(xh2[(size_t)s0 * 16 + f8]);                         \
        float4 g1 = h4_to_f4(xh2[(size_t)s1 * 16 + f8]);                         \
        float4 g2 = h4_to_f4(xh2[(size_t)s2 * 16 + f8]);                         \
        float4 g3 = h4_to_f4(xh2[(size_t)s3 * 16 + f8]);                         \
        acc.x += (g0.x + g1.x) + (g2.x + g3.x);                                  \
        acc.y += (g0.y + g1.y) + (g2.y + g3.y);                                  \
        acc.z += (g0.z + g1.z) + (g2.z + g3.z);                                  \
        acc.w += (g0.w + g1.w) + (g2.w + g3.w);                                  \
    }                                                                            \
    if (j + 8 <= deg) {                                                          \
        int s0 = (IP)[j + r4];                                                   \
        int s1 = (IP)[j + 4 + r4];                                               \
        float4 g0 = h4_to_f4(xh2[(size_t)s0 * 16 + f8]);                         \
        float4 g1 = h4_to_f4(xh2[(size_t)s1 * 16 + f8]);                         \
        acc.x += g0.x + g1.x; acc.y += g0.y + g1.y;                              \
        acc.z += g0.z + g1.z; acc.w += g0.w + g1.w;                              \
        j += 8;                                                                  \
    }                                                                            \
    for (; j < deg; j += 4) {                                                    \
        int jj = j + r4;                                                         \
        if (jj < deg) {                                                          \
            float4 g = h4_to_f4(xh2[(size_t)(IP)[jj] * 16 + f8]);                \
            acc.x += g.x; acc.y += g.y; acc.z += g.z; acc.w += g.w;              \
        }                                                                        \
    }

template<int RELU, int OUT16>
__global__ __launch_bounds__(512, 4) void sage_mfma(
        const f16* __restrict__ xh, const int* __restrict__ rowptr,
        const int* __restrict__ csr,
        const float* __restrict__ Wl, const float* __restrict__ bias,
        const float* __restrict__ Wr,
        f16* __restrict__ out16, float* __restrict__ out32, int n_nodes) {
    __shared__ __align__(16) f16 sB[16 * 512];    // 16 KB
    __shared__ __align__(16) f16 sA[8][16 * 72];  // 18 KB
    __shared__ int sIdx[8][IDXCAP];               // 12 KB

    // ---- stage B fragments: frag f = t*4+q ; q 0,1 -> Wl, q 2,3 -> Wr ----
    for (int u = threadIdx.x; u < 16 * 64; u += blockDim.x) {
        int f = u >> 6;
        int l = u & 63;
        int t = f >> 2, q = f & 3;
        const float* Wsel = (q < 2) ? Wl : Wr;
        int d  = t * 16 + (l & 15);
        int k0 = (q & 1) * 32 + (l >> 4) * 8;
        const float4* wp = (const float4*)(Wsel + d * 64 + k0);
        float4 w0 = wp[0], w1 = wp[1];
        uint4 pk;
        pk.x = __builtin_bit_cast(unsigned int, __float22half2_rn(make_float2(w0.x, w0.y)));
        pk.y = __builtin_bit_cast(unsigned int, __float22half2_rn(make_float2(w0.z, w0.w)));
        pk.z = __builtin_bit_cast(unsigned int, __float22half2_rn(make_float2(w1.x, w1.y)));
        pk.w = __builtin_bit_cast(unsigned int, __float22half2_rn(make_float2(w1.z, w1.w)));
        *(uint4*)&sB[f * 512 + l * 8] = pk;
    }
    __syncthreads();

    const int lane = threadIdx.x & 63;
    const int wid  = threadIdx.x >> 6;
    const int r4   = lane >> 4;     // edge slot / k-quarter
    const int f8   = lane & 15;     // 8-byte column within a 128B fp16 row
    f16* myA = &sA[wid][0];
    int* myIdx = &sIdx[wid][0];

    float bias_t[4];
    #pragma unroll
    for (int t = 0; t < 4; ++t) bias_t[t] = bias[t * 16 + f8];

    const int wavesPerBlock = blockDim.x >> 6;
    const int gwave = blockIdx.x * wavesPerBlock + wid;
    const int nwaves = gridDim.x * wavesPerBlock;
    const uint2* __restrict__ xh2 = (const uint2*)xh;

    for (int nb = gwave * 16; nb < n_nodes; nb += nwaves * 16) {
        // ---- rowptr window via one lane-load + readlane ----
        int rpl = 0;
        {
            int ii = nb + lane;
            if (lane < 17) rpl = rowptr[ii < n_nodes ? ii : n_nodes];
        }
        int rbase = __builtin_amdgcn_readlane(rpl, 0);
        int rend  = __builtin_amdgcn_readlane(rpl, 16);
        int cnt = rend - rbase;
        bool useLds = (cnt <= IDXCAP);

        // ---- stage batch edge indices (contiguous in csr) to LDS, coalesced ----
        if (useLds) {
            for (int c = lane; c < cnt; c += 64)
                myIdx[c] = csr[rbase + c];
        }

        // ---- prefetch root-row fragments (independent, overlaps gather) ----
        int rn = nb + f8; if (rn >= n_nodes) rn = n_nodes - 1;
        const f16x8* rrow = (const f16x8*)(xh + (size_t)rn * 64);
        f16x8 a2 = rrow[r4];                                       // root k 0..31
        f16x8 a3 = rrow[4 + r4];                                   // root k 32..63

        // ---- gather + transpose 16 nodes ----
        #pragma unroll 1
        for (int i = 0; i < 16; ++i) {
            int r0 = __builtin_amdgcn_readlane(rpl, i);
            int r1 = __builtin_amdgcn_readlane(rpl, i + 1);
            int deg = r1 - r0;
            float4 acc = make_float4(0.f, 0.f, 0.f, 0.f);
            int j = 0;
            if (useLds) {
                const int* ip = myIdx + (r0 - rbase);
                GATHER_BODY(ip)
            } else {
                const int* ip = csr + r0;
                GATHER_BODY(ip)
            }
            // butterfly across the 4 edge-slot subgroups
            acc.x += __shfl_xor(acc.x, 16, 64);
            acc.y += __shfl_xor(acc.y, 16, 64);
            acc.z += __shfl_xor(acc.z, 16, 64);
            acc.w += __shfl_xor(acc.w, 16, 64);
            acc.x += __shfl_xor(acc.x, 32, 64);
            acc.y += __shfl_xor(acc.y, 32, 64);
            acc.z += __shfl_xor(acc.z, 32, 64);
            acc.w += __shfl_xor(acc.w, 32, 64);
            float iv = 1.0f / (float)(deg > 0 ? deg : 1);
            if (r4 == (i & 3)) {
                uint2 w;
                w.x = __builtin_bit_cast(unsigned int,
                        __float22half2_rn(make_float2(acc.x * iv, acc.y * iv)));
                w.y = __builtin_bit_cast(unsigned int,
                        __float22half2_rn(make_float2(acc.z * iv, acc.w * iv)));
                *(uint2*)&myA[i * 72 + f8 * 4] = w;
            }
        }

        // ---- A fragments: mean from LDS ----
        f16x8 a0 = *(const f16x8*)&myA[f8 * 72 + r4 * 8];          // k 0..31
        f16x8 a1 = *(const f16x8*)&myA[f8 * 72 + 32 + r4 * 8];     // k 32..63

        // ---- MFMA (4 N-tiles x 4 K-chunks) + epilogue ----
        #pragma unroll
        for (int t = 0; t < 4; ++t) {
            f32x4 c = {0.f, 0.f, 0.f, 0.f};
            c = __builtin_amdgcn_mfma_f32_16x16x32_f16(a0, *(const f16x8*)&sB[(t*4+0)*512 + lane*8], c, 0, 0, 0);
            c = __builtin_amdgcn_mfma_f32_16x16x32_f16(a1, *(const f16x8*)&sB[(t*4+1)*512 + lane*8], c, 0, 0, 0);
            c = __builtin_amdgcn_mfma_f32_16x16x32_f16(a2, *(const f16x8*)&sB[(t*4+2)*512 + lane*8], c, 0, 0, 0);
            c = __builtin_amdgcn_mfma_f32_16x16x32_f16(a3, *(const f16x8*)&sB[(t*4+3)*512 + lane*8], c, 0, 0, 0);
            #pragma unroll
            for (int rr = 0; rr < 4; ++rr) {
                int n = nb + r4 * 4 + rr;           // D row = (lane>>4)*4 + reg
                if (n < n_nodes) {
                    float v = c[rr] + bias_t[t];
                    if (RELU) v = fmaxf(v, 0.f);
                    if (OUT16) out16[(size_t)n * 64 + t * 16 + f8] = (f16)v;
                    else       out32[(size_t)n * 64 + t * 16 + f8] = v;
                }
            }
        }
    }
}

// ====================== fallback (small ws): atomic scatter path ======================

__global__ void deg_kernel(const int* __restrict__ dst, float* __restrict__ deg, int E) {
    int i = blockIdx.x * blockDim.x + threadIdx.x;
    int stride = gridDim.x * blockDim.x;
    for (int e = i; e < E; e += stride)
        atomicAdd(&deg[dst[e]], 1.0f);
}

__global__ void scatter_kernel(const float* __restrict__ feat, float* __restrict__ agg,
                               const int* __restrict__ src, const int* __restrict__ dst, int E) {
    int gw = (blockIdx.x * blockDim.x + threadIdx.x) >> 6;
    int lane = threadIdx.x & 63;
    int nw = (gridDim.x * blockDim.x) >> 6;
    for (int e = gw; e < E; e += nw)
        atomicAdd(&agg[(size_t)dst[e] * D + lane], feat[(size_t)src[e] * D + lane]);
}

template<int RELU>
__global__ void combine_kernel(const float* __restrict__ xin, const float* __restrict__ agg,
                               const float* __restrict__ deg,
                               const float* __restrict__ Wl, const float* __restrict__ bias,
                               const float* __restrict__ Wr,
                               float* __restrict__ out, int n_nodes) {
    __shared__ float sWl[D * 65];
    __shared__ float sWr[D * 65];
    __shared__ float sb[D];
    __shared__ float srow[4][2][D];
    for (int i = threadIdx.x; i < D * D; i += blockDim.x) {
        int d = i >> 6, k = i & 63;
        sWl[k * 65 + d] = Wl[i];
        sWr[k * 65 + d] = Wr[i];
    }
    if (threadIdx.x < D) sb[threadIdx.x] = bias[threadIdx.x];
    __syncthreads();
    int lane = threadIdx.x & 63;
    int wid = threadIdx.x >> 6;
    for (int base = blockIdx.x * 4; base < n_nodes; base += gridDim.x * 4) {
        int n = base + wid;
        bool valid = n < n_nodes;
        if (valid) {
            float dg = deg[n];
            dg = dg > 1.0f ? dg : 1.0f;
            srow[wid][0][lane] = agg[(size_t)n * D + lane] / dg;
            srow[wid][1][lane] = xin[(size_t)n * D + lane];
        }
        __syncthreads();
        if (valid) {
            float accL = 0.f, accR = 0.f;
            #pragma unroll
            for (int k = 0; k < D; ++k) {
                accL = fmaf(srow[wid][0][k], sWl[k * 65 + lane], accL);
                accR = fmaf(srow[wid][1][k], sWr[k * 65 + lane], accR);
            }
            float rr = accL + sb[lane] + accR;
            if (RELU) rr = fmaxf(rr, 0.f);
            out[(size_t)n * D + lane] = rr;
        }
        __syncthreads();
    }
}

// ============================ launch ============================

extern "C" void kernel_launch(void* const* d_in, const int* in_sizes, int n_in,
                              void* d_out, int out_size, void* d_ws, size_t ws_size,
                              hipStream_t stream) {
    const float* x   = (const float*)d_in[0];
    const int*   ei  = (const int*)d_in[1];
    const float* W1l = (const float*)d_in[2];
    const float* b1  = (const float*)d_in[3];
    const float* W1r = (const float*)d_in[4];
    const float* W2l = (const float*)d_in[5];
    const float* b2  = (const float*)d_in[6];
    const float* W2r = (const float*)d_in[7];
    float* out = (float*)d_out;

    const int N = in_sizes[0] / D;   // 100000
    const int E = in_sizes[1] / 2;   // 1600000
    const int* src = ei;
    const int* dst = ei + E;

    const int N4 = N / 4;
    const int NB = (N4 + 255) / 256;

    size_t off = 0;
    auto alloc = [&](size_t bytes) { size_t r = off; off += (bytes + 511) & ~(size_t)511; return r; };
    size_t o_counts = alloc((size_t)N * 4);
    size_t o_rowptr = alloc((size_t)(N + 1) * 4);
    size_t o_part   = alloc((size_t)NB * 4);
    size_t o_pscan  = alloc((size_t)NB * 4);
    size_t o_csr    = alloc((size_t)E * 4);
    size_t o_xh     = alloc((size_t)N * D * 2);   // fp16 x
    size_t o_hh     = alloc((size_t)N * D * 2);   // fp16 h; also hosts rank (dead before h written)
    size_t need = off;

    bool rank_fits = (size_t)E * 4 <= (size_t)N * D * 2;

    if (ws_size >= need && (N & 3) == 0 && E >= 4 && rank_fits) {
        int* counts  = (int*)((char*)d_ws + o_counts);
        int* rowptr  = (int*)((char*)d_ws + o_rowptr);
        int* partial = (int*)((char*)d_ws + o_part);
        int* pscan   = (int*)((char*)d_ws + o_pscan);
        int* csr     = (int*)((char*)d_ws + o_csr);
        f16* xh      = (f16*)((char*)d_ws + o_xh);
        f16* hh      = (f16*)((char*)d_ws + o_hh);
        int* rank    = (int*)hh;                  // alias: rank dead before layer-1 writes hh

        hipMemsetAsync(counts, 0, (size_t)N * 4, stream);
        count_rank_convert_kernel<<<2048, 256, 0, stream>>>(dst, counts, rank, E, x, xh, N * D / 4);
        scan_block_sums<<<NB, 256, 0, stream>>>(counts, partial, N4);
        scan_partials<<<1, 64, 0, stream>>>(partial, pscan, rowptr, NB, N, E);
        scan_final<<<NB, 256, 0, stream>>>(counts, pscan, rowptr, N4);
        fill_csr2<<<2048, 256, 0, stream>>>(src, dst, rowptr, rank, csr, E);

        int wavesNeeded = (N + 15) / 16;          // 6250
        int blocks = (wavesNeeded + 7) / 8;       // 782 (8 waves/block)
        sage_mfma<1, 1><<<blocks, 512, 0, stream>>>(xh, rowptr, csr, W1l, b1, W1r, hh, nullptr, N);
        sage_mfma<0, 0><<<blocks, 512, 0, stream>>>(hh, rowptr, csr, W2l, b2, W2r, nullptr, out, N);
    } else {
        float* deg = (float*)d_ws;
        float* agg = (float*)((char*)d_ws + (((size_t)N * 4 + 511) & ~(size_t)511));
        hipMemsetAsync(deg, 0, (size_t)N * 4, stream);
        hipMemsetAsync(agg, 0, (size_t)N * D * 4, stream);
        deg_kernel<<<2048, 256, 0, stream>>>(dst, deg, E);
        scatter_kernel<<<4096, 256, 0, stream>>>(x, agg, src, dst, E);
        combine_kernel<1><<<2048, 256, 0, stream>>>(x, agg, deg, W1l, b1, W1r, out, N);
        hipMemsetAsync(agg, 0, (size_t)N * D * 4, stream);
        scatter_kernel<<<4096, 256, 0, stream>>>(out, agg, src, dst, E);
        combine_kernel<0><<<2048, 256, 0, stream>>>(out, agg, deg, W2l, b2, W2r, out, N);
    }
}